// Round 7
// baseline (81.091 us; speedup 1.0000x reference)
//
#include <hip/hip_runtime.h>
#include <hip/hip_bf16.h>
#include <math.h>

typedef _Float16 f16_t;
typedef _Float16 f16x8 __attribute__((ext_vector_type(8)));
typedef float f32x16 __attribute__((ext_vector_type(16)));
typedef unsigned int uintx4 __attribute__((ext_vector_type(4)));
typedef unsigned int uintx2 __attribute__((ext_vector_type(2)));

#define NROWS 32768
#define DD 32
#define SIG_OFF (NROWS * 64)

// ---------------- ws layout (f16 elements) ----------------
// All GEMM weights are stored in PER-WAVE FRAGMENT-LOAD ORDER:
//   [tile][ks][lane(0..63)][j(0..7)]  -> each fragment load is lane*16B,
// fully coalesced. Fragment element semantics: lane = l31 + 32*lh;
//   n = tile*32 + l31; k = ks*16 + lh*8 + j.
#define PERD_STRIDE 12416          // per-d super-block: wf2 4096 | wf3 8192 | w1 64 | b1 64
#define RW1F_OFF   397312          // 2t x 8ks x 512 = 8192   (rW1[k][n], k<128)
#define RW2F_OFF   405504          // 2t x 4ks x 512 = 4096   (rW2[k][n], k<64)
#define RW3F_OFF   409600          // 4nt x 4ks x 512 = 8192  (rW3[k][n], n<128)
#define B3F_OFF    417792          // 4t x 2ks x 512 = 4096   (b3[d][n] as B-frag, "k"=d)
#define WS_ELEMS   421888

__global__ void convert_weights(const float* __restrict__ W1,
                                const float* __restrict__ b1,
                                const float* __restrict__ W2,
                                const float* __restrict__ W3,
                                const float* __restrict__ b3,
                                const float* __restrict__ rW1,
                                const float* __restrict__ rW2,
                                const float* __restrict__ rW3,
                                f16_t* __restrict__ ws) {
  for (int i = blockIdx.x * blockDim.x + threadIdx.x; i < WS_ELEMS;
       i += gridDim.x * blockDim.x) {
    float v;
    if (i < RW1F_OFF) {
      int d = i / PERD_STRIDE;
      int r = i - d * PERD_STRIDE;
      if (r < 4096) {                 // wf2 fragments: W2[d][k][n], n<64
        int t = r >> 11, ks = (r >> 9) & 3, lane = (r >> 3) & 63, j = r & 7;
        int n = t * 32 + (lane & 31);
        int k = ks * 16 + (lane >> 5) * 8 + j;
        v = W2[(d * 64 + k) * 64 + n];
      } else if (r < 12288) {         // wf3 fragments: W3[d][k][n], n<128
        int r2 = r - 4096;
        int t = r2 >> 11, ks = (r2 >> 9) & 3, lane = (r2 >> 3) & 63, j = r2 & 7;
        int n = t * 32 + (lane & 31);
        int k = ks * 16 + (lane >> 5) * 8 + j;
        v = W3[(d * 64 + k) * 128 + n];
      } else if (r < 12352) {         // w1 (linear, broadcast-read)
        v = W1[d * 64 + (r - 12288)];
      } else {                        // b1 (linear)
        v = b1[d * 64 + (r - 12352)];
      }
    } else if (i < RW2F_OFF) {        // rW1 fragments, k<128
      int i2 = i - RW1F_OFF;
      int t = i2 >> 12, ks = (i2 >> 9) & 7, lane = (i2 >> 3) & 63, j = i2 & 7;
      int n = t * 32 + (lane & 31);
      int k = ks * 16 + (lane >> 5) * 8 + j;
      v = rW1[k * 64 + n];
    } else if (i < RW3F_OFF) {        // rW2 fragments, k<64
      int i2 = i - RW2F_OFF;
      int t = i2 >> 11, ks = (i2 >> 9) & 3, lane = (i2 >> 3) & 63, j = i2 & 7;
      int n = t * 32 + (lane & 31);
      int k = ks * 16 + (lane >> 5) * 8 + j;
      v = rW2[k * 64 + n];
    } else if (i < B3F_OFF) {         // rW3 fragments, output col n<128, k<64
      int i2 = i - RW3F_OFF;
      int nt = i2 >> 11, ks = (i2 >> 9) & 3, lane = (i2 >> 3) & 63, j = i2 & 7;
      int n = nt * 32 + (lane & 31);
      int k = ks * 16 + (lane >> 5) * 8 + j;
      v = rW3[k * 128 + n];
    } else {                          // b3 as B-fragment: "k" axis = d (32)
      int i2 = i - B3F_OFF;
      int t = i2 >> 10, ks = (i2 >> 9) & 1, lane = (i2 >> 3) & 63, j = i2 & 7;
      int n = t * 32 + (lane & 31);
      int dsrc = ks * 16 + (lane >> 5) * 8 + j;
      v = b3[dsrc * 128 + n];
    }
    ws[i] = (f16_t)v;
  }
}

// Transpose a swapped-GEMM C tile (lane = data-row l31, regs = 16 n-values:
// n = (reg&3)+8*(reg>>2)+4*lh) into two B fragments (lane supplies
// n = 16*kk + 8*lh + j, j=0..7 contiguous) via a PER-WAVE private LDS
// round-trip. Within-wave ds_write->ds_read ordering is a compiler-visible
// LDS dependence (lgkmcnt inserted automatically) -- no barrier needed.
__device__ __forceinline__ void xpose2(const f32x16& c, unsigned* row, int lh,
                                       f16x8& o0, f16x8& o1) {
  #pragma unroll
  for (int a = 0; a < 4; ++a) {
    uintx2 w;
    w.x = __builtin_bit_cast(unsigned, __builtin_amdgcn_cvt_pkrtz(c[4 * a + 0], c[4 * a + 1]));
    w.y = __builtin_bit_cast(unsigned, __builtin_amdgcn_cvt_pkrtz(c[4 * a + 2], c[4 * a + 3]));
    *reinterpret_cast<uintx2*>(row + 4 * a + 2 * lh) = w;
  }
  uintx2 ra = *reinterpret_cast<const uintx2*>(row + 4 * lh);
  uintx2 rb = *reinterpret_cast<const uintx2*>(row + 4 * lh + 2);
  uintx2 rc = *reinterpret_cast<const uintx2*>(row + 8 + 4 * lh);
  uintx2 rd = *reinterpret_cast<const uintx2*>(row + 8 + 4 * lh + 2);
  uintx4 w0 = {ra.x, ra.y, rb.x, rb.y};
  uintx4 w1 = {rc.x, rc.y, rd.x, rd.y};
  o0 = __builtin_bit_cast(f16x8, w0);
  o1 = __builtin_bit_cast(f16x8, w1);
}

// Block = 256 thr = 4 waves = 2 pairs. Pair p owns rows blk*64+p*32+(lane&31).
// Wave parity q: d-range [q*16, q*16+16). All layer GEMMs are computed
// swapped (C' = W^T x act^T) so activations stay lane-local; transposes via
// per-wave LDS round-trip (xpose2). Pool accumulates inside the GEMM2 MFMA
// accumulator across d (mask folded into h2). Barriers: 2 total.
// Round 7: __launch_bounds__(256,1) -- the d-loop needs ~230 live VGPRs
// (acc 64 + hacc 32 + 24 in-flight weight fragments 96 + addressing); the
// (256,2) 128-reg cap forced scratch spills (r6: WRITE 16.4->22.5MB).
// At 256 VGPR the HW still fits 8 waves/CU = 2 blocks/CU (m69 ladder), the
// same residency as before -- zero occupancy cost.
__launch_bounds__(256, 1)
__global__ void indexnet_main(const float* __restrict__ x,
                              const int* __restrict__ mask,
                              const float* __restrict__ b2,
                              const float* __restrict__ rb1,
                              const float* __restrict__ rb2,
                              const float* __restrict__ rb3,
                              const f16_t* __restrict__ ws,
                              float* __restrict__ out) {
  __shared__ float b2_lds[32][64];
  __shared__ float rb_lds[256];                        // rb1 | rb2 | rb3
  __shared__ float pool_lds[2][2][32][68];             // [pair][lh][l31][64+pad]
  __shared__ __align__(16) unsigned xp_lds[4][2][32][18];  // per-wave xpose scratch

  const int tid = threadIdx.x;
  const int lane = tid & 63;
  const int wid = tid >> 6;
  const int p = wid >> 1;          // pair (row group)
  const int q = wid & 1;           // d-range half
  const int l31 = lane & 31;
  const int lh = lane >> 5;
  const int row0 = blockIdx.x * 64;
  const int lane16 = lane * 8;     // f16 offset of this lane's 16B fragment chunk

  unsigned* xrow0 = &xp_lds[wid][0][l31][0];
  unsigned* xrow1 = &xp_lds[wid][1][l31][0];

  // ---- stage b2 [32][64] (flat copy) ----
  {
    float4* dst = reinterpret_cast<float4*>(&b2_lds[0][0]);
    const float4* src = reinterpret_cast<const float4*>(b2);
    dst[tid * 2] = src[tid * 2];
    dst[tid * 2 + 1] = src[tid * 2 + 1];
  }
  // ---- stage readout biases ----
  if (tid < 64)       rb_lds[tid] = rb1[tid];
  else if (tid < 128) rb_lds[tid] = rb2[tid - 64];
  else                rb_lds[tid] = rb3[tid - 128];

  // ---- per-lane mask word for own row ----
  unsigned mword = 0;
  {
    const int4* mrow = reinterpret_cast<const int4*>(mask + (size_t)(row0 + p * 32 + l31) * DD);
    #pragma unroll
    for (int c4 = 0; c4 < 8; ++c4) {
      int4 m = mrow[c4];
      mword |= (m.x != 0 ? 1u : 0u) << (4 * c4);
      mword |= (m.y != 0 ? 1u : 0u) << (4 * c4 + 1);
      mword |= (m.z != 0 ? 1u : 0u) << (4 * c4 + 2);
      mword |= (m.w != 0 ? 1u : 0u) << (4 * c4 + 3);
    }
  }
  // ---- per-lane x row (own 16 d's) stays in global; loaded per 4-group ----
  const float* xrow = x + (size_t)(row0 + p * 32 + l31) * DD + q * 16;

  __syncthreads();   // barrier #1 (b2_lds, rb_lds ready)

  f32x16 acc[4] = {};     // pooled^T accumulator: tile t -> n = 32t + rl, lane = row
  const int dbase = q * 16;

  for (int dd0 = 0; dd0 < 16; dd0 += 4) {
    // 4 d-values of x for this group (one coalesced-ish float4, 8 per kernel)
    float4 xv4 = *reinterpret_cast<const float4*>(xrow + dd0);
    #pragma unroll
    for (int j = 0; j < 4; ++j) {
      const int d = dbase + dd0 + j;
      const f16_t* base = ws + (size_t)d * PERD_STRIDE;

      // ---- batched weight-fragment loads: 24 coalesced 16B/lane loads ----
      f16x8 wf2[2][4], wf3[4][4];
      #pragma unroll
      for (int t = 0; t < 2; ++t)
        #pragma unroll
        for (int ks = 0; ks < 4; ++ks)
          wf2[t][ks] = *reinterpret_cast<const f16x8*>(base + (t * 4 + ks) * 512 + lane16);
      #pragma unroll
      for (int t = 0; t < 4; ++t)
        #pragma unroll
        for (int ks = 0; ks < 4; ++ks)
          wf3[t][ks] = *reinterpret_cast<const f16x8*>(base + 4096 + (t * 4 + ks) * 512 + lane16);

      // ---- h1 fragments in packed f16: h1[l31][16ks+8lh+j] ----
      float xv = (j == 0) ? xv4.x : (j == 1) ? xv4.y : (j == 2) ? xv4.z : xv4.w;
      f16_t xh = (f16_t)xv;
      f16x8 xv8 = {xh, xh, xh, xh, xh, xh, xh, xh};
      f16x8 h1f[4];
      const f16_t* w1p = base + 12288 + lh * 8;
      const f16_t* b1p = base + 12352 + lh * 8;
      #pragma unroll
      for (int ks = 0; ks < 4; ++ks) {
        f16x8 w1 = *reinterpret_cast<const f16x8*>(w1p + ks * 16);
        f16x8 bb = *reinterpret_cast<const f16x8*>(b1p + ks * 16);
        f16x8 h = xv8 * w1 + bb;
        h1f[ks] = __builtin_elementwise_max(h, (f16x8)(f16_t)0);
      }

      // ---- GEMM1 (swapped): h2^T = W2T x h1^T, acc init = b2 ----
      f32x16 hacc[2];
      #pragma unroll
      for (int t = 0; t < 2; ++t)
        #pragma unroll
        for (int a = 0; a < 4; ++a) {
          float4 bv = *reinterpret_cast<const float4*>(&b2_lds[d][t * 32 + a * 8 + lh * 4]);
          hacc[t][4 * a + 0] = bv.x; hacc[t][4 * a + 1] = bv.y;
          hacc[t][4 * a + 2] = bv.z; hacc[t][4 * a + 3] = bv.w;
        }
      #pragma unroll
      for (int ks = 0; ks < 4; ++ks) {
        hacc[0] = __builtin_amdgcn_mfma_f32_32x32x16_f16(wf2[0][ks], h1f[ks], hacc[0], 0, 0, 0);
        hacc[1] = __builtin_amdgcn_mfma_f32_32x32x16_f16(wf2[1][ks], h1f[ks], hacc[1], 0, 0, 0);
      }
      // relu + mask (lane = data row for C cols)
      const bool mb = (mword >> d) & 1u;
      #pragma unroll
      for (int t = 0; t < 2; ++t)
        #pragma unroll
        for (int r = 0; r < 16; ++r) {
          float v = fmaxf(hacc[t][r], 0.f);
          hacc[t][r] = mb ? v : 0.f;
        }
      // LDS-based in-wave transpose -> GEMM2 B fragments
      f16x8 pf[4];
      xpose2(hacc[0], xrow0, lh, pf[0], pf[1]);
      xpose2(hacc[1], xrow1, lh, pf[2], pf[3]);

      // ---- GEMM2 (swapped): pooled^T += W3T x (m*h2)^T  (acc across d) ----
      #pragma unroll
      for (int t = 0; t < 4; ++t)
        #pragma unroll
        for (int ks = 0; ks < 4; ++ks)
          acc[t] = __builtin_amdgcn_mfma_f32_32x32x16_f16(wf3[t][ks], pf[ks], acc[t], 0, 0, 0);
    }
  }

  // ---- pool combine across the wave pair ----
  if (q == 1) {
    #pragma unroll
    for (int t = 0; t < 4; ++t)
      #pragma unroll
      for (int a = 0; a < 4; ++a) {
        float4 f = {acc[t][4 * a], acc[t][4 * a + 1], acc[t][4 * a + 2], acc[t][4 * a + 3]};
        *reinterpret_cast<float4*>(&pool_lds[p][lh][l31][(t * 4 + a) * 4]) = f;
      }
  }
  __syncthreads();   // barrier #2
  if (q == 1) return;

  #pragma unroll
  for (int t = 0; t < 4; ++t)
    #pragma unroll
    for (int a = 0; a < 4; ++a) {
      float4 f = *reinterpret_cast<const float4*>(&pool_lds[p][lh][l31][(t * 4 + a) * 4]);
      acc[t][4 * a + 0] += f.x; acc[t][4 * a + 1] += f.y;
      acc[t][4 * a + 2] += f.z; acc[t][4 * a + 3] += f.w;
    }

  // ---- pooled += maskT @ b3 (bias of masked sum), 8 MFMA ----
  {
    f16x8 mf[2];
    #pragma unroll
    for (int ks = 0; ks < 2; ++ks) {
      unsigned w[4];
      #pragma unroll
      for (int i = 0; i < 4; ++i) {
        int d0 = ks * 16 + lh * 8 + 2 * i;
        w[i] = (((mword >> d0) & 1u) ? 0x3C00u : 0u) |
               (((mword >> (d0 + 1)) & 1u) ? 0x3C000000u : 0u);
      }
      uintx4 ww = {w[0], w[1], w[2], w[3]};
      mf[ks] = __builtin_bit_cast(f16x8, ww);
    }
    const f16_t* b3f = ws + B3F_OFF;
    #pragma unroll
    for (int t = 0; t < 4; ++t)
      #pragma unroll
      for (int ks = 0; ks < 2; ++ks) {
        f16x8 bf = *reinterpret_cast<const f16x8*>(b3f + (t * 2 + ks) * 512 + lane16);
        acc[t] = __builtin_amdgcn_mfma_f32_32x32x16_f16(bf, mf[ks], acc[t], 0, 0, 0);
      }
  }

  // ---- R1 (swapped): r1^T = rW1T x pooled^T, K=128 ----
  f16x8 poolf[8];
  xpose2(acc[0], xrow0, lh, poolf[0], poolf[1]);
  xpose2(acc[1], xrow1, lh, poolf[2], poolf[3]);
  xpose2(acc[2], xrow0, lh, poolf[4], poolf[5]);
  xpose2(acc[3], xrow1, lh, poolf[6], poolf[7]);
  f32x16 r1[2];
  #pragma unroll
  for (int t = 0; t < 2; ++t)
    #pragma unroll
    for (int a = 0; a < 4; ++a) {
      float4 bv = *reinterpret_cast<const float4*>(&rb_lds[t * 32 + a * 8 + lh * 4]);
      r1[t][4 * a + 0] = bv.x; r1[t][4 * a + 1] = bv.y;
      r1[t][4 * a + 2] = bv.z; r1[t][4 * a + 3] = bv.w;
    }
  {
    const f16_t* rw1 = ws + RW1F_OFF;
    #pragma unroll
    for (int t = 0; t < 2; ++t)
      #pragma unroll
      for (int ks = 0; ks < 8; ++ks) {
        f16x8 wf = *reinterpret_cast<const f16x8*>(rw1 + (t * 8 + ks) * 512 + lane16);
        r1[t] = __builtin_amdgcn_mfma_f32_32x32x16_f16(wf, poolf[ks], r1[t], 0, 0, 0);
      }
  }
  #pragma unroll
  for (int t = 0; t < 2; ++t)
    #pragma unroll
    for (int r = 0; r < 16; ++r) r1[t][r] = fmaxf(r1[t][r], 0.f);

  // ---- R2 (swapped): r2^T = rW2T x r1^T, K=64 ----
  f16x8 r1f[4];
  xpose2(r1[0], xrow0, lh, r1f[0], r1f[1]);
  xpose2(r1[1], xrow1, lh, r1f[2], r1f[3]);
  f32x16 r2[2];
  #pragma unroll
  for (int t = 0; t < 2; ++t)
    #pragma unroll
    for (int a = 0; a < 4; ++a) {
      float4 bv = *reinterpret_cast<const float4*>(&rb_lds[64 + t * 32 + a * 8 + lh * 4]);
      r2[t][4 * a + 0] = bv.x; r2[t][4 * a + 1] = bv.y;
      r2[t][4 * a + 2] = bv.z; r2[t][4 * a + 3] = bv.w;
    }
  {
    const f16_t* rw2 = ws + RW2F_OFF;
    #pragma unroll
    for (int t = 0; t < 2; ++t)
      #pragma unroll
      for (int ks = 0; ks < 4; ++ks) {
        f16x8 wf = *reinterpret_cast<const f16x8*>(rw2 + (t * 4 + ks) * 512 + lane16);
        r2[t] = __builtin_amdgcn_mfma_f32_32x32x16_f16(wf, r1f[ks], r2[t], 0, 0, 0);
      }
  }
  #pragma unroll
  for (int t = 0; t < 2; ++t)
    #pragma unroll
    for (int r = 0; r < 16; ++r) r2[t][r] = fmaxf(r2[t][r], 0.f);

  // ---- R3 (NON-swapped for coalesced stores): o = r2 @ rW3, N=128 ----
  f16x8 r2f[4];
  xpose2(r2[0], xrow0, lh, r2f[0], r2f[1]);
  xpose2(r2[1], xrow1, lh, r2f[2], r2f[3]);
  f32x16 oacc[4] = {};
  {
    const f16_t* rw3 = ws + RW3F_OFF;
    #pragma unroll
    for (int nt = 0; nt < 4; ++nt)
      #pragma unroll
      for (int ks = 0; ks < 4; ++ks) {
        f16x8 wf = *reinterpret_cast<const f16x8*>(rw3 + (nt * 4 + ks) * 512 + lane16);
        oacc[nt] = __builtin_amdgcn_mfma_f32_32x32x16_f16(r2f[ks], wf, oacc[nt], 0, 0, 0);
      }
  }
  const int rowb = row0 + p * 32;
  #pragma unroll
  for (int nt = 0; nt < 4; ++nt) {
    float rbv = rb_lds[128 + nt * 32 + l31];
    #pragma unroll
    for (int r = 0; r < 16; ++r) {
      int rl = (r & 3) + 8 * (r >> 2) + 4 * lh;
      size_t grow = (size_t)(rowb + rl);
      float v = oacc[nt][r] + rbv;
      if (nt < 2) {
        out[grow * 64 + nt * 32 + l31] = v;
      } else {
        float sp = fmaxf(v, 0.f) + __logf(1.f + __expf(-fabsf(v)));
        out[(size_t)SIG_OFF + grow * 64 + (nt - 2) * 32 + l31] = sp;
      }
    }
  }
}

extern "C" void kernel_launch(void* const* d_in, const int* in_sizes, int n_in,
                              void* d_out, int out_size, void* d_ws, size_t ws_size,
                              hipStream_t stream) {
  const float* x    = (const float*)d_in[0];
  const int*   mask = (const int*)d_in[1];
  const float* W1   = (const float*)d_in[2];
  const float* b1   = (const float*)d_in[3];
  const float* W2   = (const float*)d_in[4];
  const float* b2   = (const float*)d_in[5];
  const float* W3   = (const float*)d_in[6];
  const float* b3   = (const float*)d_in[7];
  const float* rW1  = (const float*)d_in[8];
  const float* rb1  = (const float*)d_in[9];
  const float* rW2  = (const float*)d_in[10];
  const float* rb2  = (const float*)d_in[11];
  const float* rW3  = (const float*)d_in[12];
  const float* rb3  = (const float*)d_in[13];
  float* out = (float*)d_out;
  f16_t* ws = (f16_t*)d_ws;

  convert_weights<<<256, 256, 0, stream>>>(W1, b1, W2, W3, b3, rW1, rW2, rW3, ws);
  indexnet_main<<<NROWS / 64, 256, 0, stream>>>(
      x, mask, b2, rb1, rb2, rb3, ws, out);
}

// Round 8
// 62.230 us; speedup vs baseline: 1.3031x; 1.3031x over previous
//
#include <hip/hip_runtime.h>
#include <hip/hip_bf16.h>
#include <math.h>

typedef _Float16 f16_t;
typedef _Float16 f16x8 __attribute__((ext_vector_type(8)));
typedef float f32x16 __attribute__((ext_vector_type(16)));
typedef unsigned int uintx4 __attribute__((ext_vector_type(4)));
typedef unsigned int uintx2 __attribute__((ext_vector_type(2)));

#define NROWS 32768
#define DD 32
#define SIG_OFF (NROWS * 64)

// ---------------- ws layout (f16 elements) ----------------
// GEMM weights in PER-WAVE FRAGMENT-LOAD ORDER: [tile][ks][lane][j(0..7)],
// lane = l31 + 32*lh; n = tile*32 + l31; k = ks*16 + lh*8 + j.
// Round 8: per-d superblock is now exactly wf2(4096) | wf3(8192) = 12288 f16
// = 24KB (DMA-friendly); w1/b1 live in their own linear region staged once.
#define PERD_STRIDE 12288
#define W1B1F_OFF  393216          // [32 d][128] : w1[0..63] | b1[64..127]
#define RW1F_OFF   397312          // 2t x 8ks x 512 (rW1[k][n], k<128)
#define RW2F_OFF   405504          // 2t x 4ks x 512 (rW2[k][n], k<64)
#define RW3F_OFF   409600          // 4nt x 4ks x 512 (rW3[k][n], n<128)
#define B3F_OFF    417792          // 4t x 2ks x 512 (b3[d][n] as B-frag, "k"=d)
#define WS_ELEMS   421888

__global__ void convert_weights(const float* __restrict__ W1,
                                const float* __restrict__ b1,
                                const float* __restrict__ W2,
                                const float* __restrict__ W3,
                                const float* __restrict__ b3,
                                const float* __restrict__ rW1,
                                const float* __restrict__ rW2,
                                const float* __restrict__ rW3,
                                f16_t* __restrict__ ws) {
  for (int i = blockIdx.x * blockDim.x + threadIdx.x; i < WS_ELEMS;
       i += gridDim.x * blockDim.x) {
    float v;
    if (i < W1B1F_OFF) {
      int d = i / PERD_STRIDE;
      int r = i - d * PERD_STRIDE;
      if (r < 4096) {                 // wf2 fragments: W2[d][k][n], n<64
        int t = r >> 11, ks = (r >> 9) & 3, lane = (r >> 3) & 63, j = r & 7;
        int n = t * 32 + (lane & 31);
        int k = ks * 16 + (lane >> 5) * 8 + j;
        v = W2[(d * 64 + k) * 64 + n];
      } else {                        // wf3 fragments: W3[d][k][n], n<128
        int r2 = r - 4096;
        int t = r2 >> 11, ks = (r2 >> 9) & 3, lane = (r2 >> 3) & 63, j = r2 & 7;
        int n = t * 32 + (lane & 31);
        int k = ks * 16 + (lane >> 5) * 8 + j;
        v = W3[(d * 64 + k) * 128 + n];
      }
    } else if (i < RW1F_OFF) {        // w1 | b1, [d][128]
      int jj = i - W1B1F_OFF;
      int d = jj >> 7, c = jj & 127;
      v = (c < 64) ? W1[d * 64 + c] : b1[d * 64 + (c - 64)];
    } else if (i < RW2F_OFF) {        // rW1 fragments, k<128
      int i2 = i - RW1F_OFF;
      int t = i2 >> 12, ks = (i2 >> 9) & 7, lane = (i2 >> 3) & 63, j = i2 & 7;
      int n = t * 32 + (lane & 31);
      int k = ks * 16 + (lane >> 5) * 8 + j;
      v = rW1[k * 64 + n];
    } else if (i < RW3F_OFF) {        // rW2 fragments, k<64
      int i2 = i - RW2F_OFF;
      int t = i2 >> 11, ks = (i2 >> 9) & 3, lane = (i2 >> 3) & 63, j = i2 & 7;
      int n = t * 32 + (lane & 31);
      int k = ks * 16 + (lane >> 5) * 8 + j;
      v = rW2[k * 64 + n];
    } else if (i < B3F_OFF) {         // rW3 fragments, output col n<128, k<64
      int i2 = i - RW3F_OFF;
      int nt = i2 >> 11, ks = (i2 >> 9) & 3, lane = (i2 >> 3) & 63, j = i2 & 7;
      int n = nt * 32 + (lane & 31);
      int k = ks * 16 + (lane >> 5) * 8 + j;
      v = rW3[k * 128 + n];
    } else {                          // b3 as B-fragment: "k" axis = d (32)
      int i2 = i - B3F_OFF;
      int t = i2 >> 10, ks = (i2 >> 9) & 1, lane = (i2 >> 3) & 63, j = i2 & 7;
      int n = t * 32 + (lane & 31);
      int dsrc = ks * 16 + (lane >> 5) * 8 + j;
      v = b3[dsrc * 128 + n];
    }
    ws[i] = (f16_t)v;
  }
}

// Swapped-C tile (lane = data-row l31, regs: n=(reg&3)+8*(reg>>2)+4*lh) ->
// two B fragments via a PER-WAVE private LDS round-trip (no barrier; the
// within-wave ds_write->ds_read dependence is compiler-ordered).
__device__ __forceinline__ void xpose2(const f32x16& c, unsigned* row, int lh,
                                       f16x8& o0, f16x8& o1) {
  #pragma unroll
  for (int a = 0; a < 4; ++a) {
    uintx2 w;
    w.x = __builtin_bit_cast(unsigned, __builtin_amdgcn_cvt_pkrtz(c[4 * a + 0], c[4 * a + 1]));
    w.y = __builtin_bit_cast(unsigned, __builtin_amdgcn_cvt_pkrtz(c[4 * a + 2], c[4 * a + 3]));
    *reinterpret_cast<uintx2*>(row + 4 * a + 2 * lh) = w;
  }
  uintx2 ra = *reinterpret_cast<const uintx2*>(row + 4 * lh);
  uintx2 rb = *reinterpret_cast<const uintx2*>(row + 4 * lh + 2);
  uintx2 rc = *reinterpret_cast<const uintx2*>(row + 8 + 4 * lh);
  uintx2 rd = *reinterpret_cast<const uintx2*>(row + 8 + 4 * lh + 2);
  uintx4 w0 = {ra.x, ra.y, rb.x, rb.y};
  uintx4 w1 = {rc.x, rc.y, rd.x, rd.y};
  o0 = __builtin_bit_cast(f16x8, w0);
  o1 = __builtin_bit_cast(f16x8, w1);
}

// Round 8 structure: block = 256 thr = 4 waves = 128 rows (wave wid owns rows
// blk*128 + wid*32 + l31). NO d-split: all waves walk d=0..31 sharing one
// LDS-staged 24KB weight superblock per d, double-buffered (reg-staged T14:
// issue global loads for d+1 -> compute d from LDS -> ds_write -> barrier).
// Pool accumulates fully per wave (no combine). Weights hit each wave as
// ds_read_b128 (~120cyc) instead of ~400cyc L2 gathers; HBM/L2 latency of the
// next superblock hides under the current d's ~800cyc of compute.
__launch_bounds__(256, 1)
__global__ void indexnet_main(const float* __restrict__ x,
                              const int* __restrict__ mask,
                              const float* __restrict__ b2,
                              const float* __restrict__ rb1,
                              const float* __restrict__ rb2,
                              const float* __restrict__ rb3,
                              const f16_t* __restrict__ ws,
                              float* __restrict__ out) {
  __shared__ __align__(16) f16_t wbuf[2][12288];       // 48KB weight dbuf
  __shared__ __align__(16) f16_t w1b1_lds[32][128];    // 8KB
  __shared__ float b2_lds[32][64];                     // 8KB
  __shared__ float rb_lds[256];                        // rb1 | rb2 | rb3
  __shared__ __align__(16) unsigned xp_lds[4][2][32][18];  // per-wave xpose

  const int tid = threadIdx.x;
  const int lane = tid & 63;
  const int wid = tid >> 6;
  const int l31 = lane & 31;
  const int lh = lane >> 5;
  const int row0 = blockIdx.x * 128;
  const int lane16 = lane * 8;            // f16 offset of lane's 16B chunk
  const int schunk = wid * 512 + lane16;  // thread's slot within a 4KB round

  unsigned* xrow0 = &xp_lds[wid][0][l31][0];
  unsigned* xrow1 = &xp_lds[wid][1][l31][0];

  // ---- stage b2 [32][64] f32 ----
  {
    float4* dst = reinterpret_cast<float4*>(&b2_lds[0][0]);
    const float4* src = reinterpret_cast<const float4*>(b2);
    dst[tid * 2] = src[tid * 2];
    dst[tid * 2 + 1] = src[tid * 2 + 1];
  }
  // ---- stage readout biases ----
  if (tid < 64)       rb_lds[tid] = rb1[tid];
  else if (tid < 128) rb_lds[tid] = rb2[tid - 64];
  else                rb_lds[tid] = rb3[tid - 128];
  // ---- stage w1|b1 [32][128] f16 (8KB) ----
  {
    const uintx4* src = reinterpret_cast<const uintx4*>(ws + W1B1F_OFF);
    uintx4* dst = reinterpret_cast<uintx4*>(&w1b1_lds[0][0]);
    dst[tid * 2] = src[tid * 2];
    dst[tid * 2 + 1] = src[tid * 2 + 1];
  }
  // ---- per-lane mask word for own row ----
  unsigned mword = 0;
  {
    const int4* mrow = reinterpret_cast<const int4*>(mask + (size_t)(row0 + wid * 32 + l31) * DD);
    #pragma unroll
    for (int c4 = 0; c4 < 8; ++c4) {
      int4 m = mrow[c4];
      mword |= (m.x != 0 ? 1u : 0u) << (4 * c4);
      mword |= (m.y != 0 ? 1u : 0u) << (4 * c4 + 1);
      mword |= (m.z != 0 ? 1u : 0u) << (4 * c4 + 2);
      mword |= (m.w != 0 ? 1u : 0u) << (4 * c4 + 3);
    }
  }
  const float* xrow = x + (size_t)(row0 + wid * 32 + l31) * DD;

  // ---- prologue: stage d=0 superblock into wbuf[0] ----
  #pragma unroll
  for (int r = 0; r < 6; ++r) {
    f16x8 v = *reinterpret_cast<const f16x8*>(ws + r * 2048 + schunk);
    *reinterpret_cast<f16x8*>(&wbuf[0][r * 2048 + schunk]) = v;
  }
  __syncthreads();   // staging + b2/rb/w1b1 ready

  f32x16 acc[4] = {};   // pooled^T: tile t -> n = 32t + rl, lane = row
  int cur = 0;

  for (int dd0 = 0; dd0 < 32; dd0 += 4) {
    float4 xv4 = *reinterpret_cast<const float4*>(xrow + dd0);
    #pragma unroll
    for (int j = 0; j < 4; ++j) {
      const int d = dd0 + j;
      // ---- issue next-superblock global loads (T14: issue-early) ----
      f16x8 st0, st1, st2, st3, st4, st5;
      const bool pf_on = (d + 1 < 32);
      if (pf_on) {
        const f16_t* wsrc = ws + (size_t)(d + 1) * PERD_STRIDE + schunk;
        st0 = *reinterpret_cast<const f16x8*>(wsrc);
        st1 = *reinterpret_cast<const f16x8*>(wsrc + 2048);
        st2 = *reinterpret_cast<const f16x8*>(wsrc + 4096);
        st3 = *reinterpret_cast<const f16x8*>(wsrc + 6144);
        st4 = *reinterpret_cast<const f16x8*>(wsrc + 8192);
        st5 = *reinterpret_cast<const f16x8*>(wsrc + 10240);
      }

      // ---- fragment reads from LDS (batched, independent) ----
      const f16_t* wb = &wbuf[cur][0];
      f16x8 wf2[2][4], wf3[4][4];
      #pragma unroll
      for (int t = 0; t < 2; ++t)
        #pragma unroll
        for (int ks = 0; ks < 4; ++ks)
          wf2[t][ks] = *reinterpret_cast<const f16x8*>(wb + (t * 4 + ks) * 512 + lane16);
      #pragma unroll
      for (int t = 0; t < 4; ++t)
        #pragma unroll
        for (int ks = 0; ks < 4; ++ks)
          wf3[t][ks] = *reinterpret_cast<const f16x8*>(wb + 4096 + (t * 4 + ks) * 512 + lane16);

      // ---- h1 fragments (w1/b1 from LDS, broadcast reads) ----
      float xv = (j == 0) ? xv4.x : (j == 1) ? xv4.y : (j == 2) ? xv4.z : xv4.w;
      f16_t xh = (f16_t)xv;
      f16x8 xv8 = {xh, xh, xh, xh, xh, xh, xh, xh};
      f16x8 h1f[4];
      #pragma unroll
      for (int ks = 0; ks < 4; ++ks) {
        f16x8 w1 = *reinterpret_cast<const f16x8*>(&w1b1_lds[d][ks * 16 + lh * 8]);
        f16x8 bb = *reinterpret_cast<const f16x8*>(&w1b1_lds[d][64 + ks * 16 + lh * 8]);
        f16x8 h = xv8 * w1 + bb;
        h1f[ks] = __builtin_elementwise_max(h, (f16x8)(f16_t)0);
      }

      // ---- GEMM1 (swapped): h2^T = W2T x h1^T, acc init = b2 ----
      f32x16 hacc[2];
      #pragma unroll
      for (int t = 0; t < 2; ++t)
        #pragma unroll
        for (int a = 0; a < 4; ++a) {
          float4 bv = *reinterpret_cast<const float4*>(&b2_lds[d][t * 32 + a * 8 + lh * 4]);
          hacc[t][4 * a + 0] = bv.x; hacc[t][4 * a + 1] = bv.y;
          hacc[t][4 * a + 2] = bv.z; hacc[t][4 * a + 3] = bv.w;
        }
      #pragma unroll
      for (int ks = 0; ks < 4; ++ks) {
        hacc[0] = __builtin_amdgcn_mfma_f32_32x32x16_f16(wf2[0][ks], h1f[ks], hacc[0], 0, 0, 0);
        hacc[1] = __builtin_amdgcn_mfma_f32_32x32x16_f16(wf2[1][ks], h1f[ks], hacc[1], 0, 0, 0);
      }
      // relu + mask (lane = data row)
      const bool mb = (mword >> d) & 1u;
      #pragma unroll
      for (int t = 0; t < 2; ++t)
        #pragma unroll
        for (int r = 0; r < 16; ++r) {
          float v = fmaxf(hacc[t][r], 0.f);
          hacc[t][r] = mb ? v : 0.f;
        }
      // in-wave LDS transpose -> GEMM2 B fragments
      f16x8 pf[4];
      xpose2(hacc[0], xrow0, lh, pf[0], pf[1]);
      xpose2(hacc[1], xrow1, lh, pf[2], pf[3]);

      // ---- GEMM2 (swapped): pooled^T += W3T x (m*h2)^T ----
      #pragma unroll
      for (int t = 0; t < 4; ++t)
        #pragma unroll
        for (int ks = 0; ks < 4; ++ks)
          acc[t] = __builtin_amdgcn_mfma_f32_32x32x16_f16(wf3[t][ks], pf[ks], acc[t], 0, 0, 0);

      // ---- write staged superblock to the other buffer (T14: write-late) ----
      if (pf_on) {
        f16_t* wn = &wbuf[cur ^ 1][0];
        *reinterpret_cast<f16x8*>(wn + schunk)         = st0;
        *reinterpret_cast<f16x8*>(wn + 2048 + schunk)  = st1;
        *reinterpret_cast<f16x8*>(wn + 4096 + schunk)  = st2;
        *reinterpret_cast<f16x8*>(wn + 6144 + schunk)  = st3;
        *reinterpret_cast<f16x8*>(wn + 8192 + schunk)  = st4;
        *reinterpret_cast<f16x8*>(wn + 10240 + schunk) = st5;
      }
      __syncthreads();
      cur ^= 1;
    }
  }

  // ---- pooled += maskT @ b3 (bias of masked sum), 8 MFMA ----
  {
    f16x8 mf[2];
    #pragma unroll
    for (int ks = 0; ks < 2; ++ks) {
      unsigned w[4];
      #pragma unroll
      for (int i = 0; i < 4; ++i) {
        int d0 = ks * 16 + lh * 8 + 2 * i;
        w[i] = (((mword >> d0) & 1u) ? 0x3C00u : 0u) |
               (((mword >> (d0 + 1)) & 1u) ? 0x3C000000u : 0u);
      }
      uintx4 ww = {w[0], w[1], w[2], w[3]};
      mf[ks] = __builtin_bit_cast(f16x8, ww);
    }
    const f16_t* b3f = ws + B3F_OFF;
    #pragma unroll
    for (int t = 0; t < 4; ++t)
      #pragma unroll
      for (int ks = 0; ks < 2; ++ks) {
        f16x8 bf = *reinterpret_cast<const f16x8*>(b3f + (t * 2 + ks) * 512 + lane16);
        acc[t] = __builtin_amdgcn_mfma_f32_32x32x16_f16(bf, mf[ks], acc[t], 0, 0, 0);
      }
  }

  // ---- R1 (swapped): r1^T = rW1T x pooled^T, K=128 ----
  f16x8 poolf[8];
  xpose2(acc[0], xrow0, lh, poolf[0], poolf[1]);
  xpose2(acc[1], xrow1, lh, poolf[2], poolf[3]);
  xpose2(acc[2], xrow0, lh, poolf[4], poolf[5]);
  xpose2(acc[3], xrow1, lh, poolf[6], poolf[7]);
  f32x16 r1[2];
  #pragma unroll
  for (int t = 0; t < 2; ++t)
    #pragma unroll
    for (int a = 0; a < 4; ++a) {
      float4 bv = *reinterpret_cast<const float4*>(&rb_lds[t * 32 + a * 8 + lh * 4]);
      r1[t][4 * a + 0] = bv.x; r1[t][4 * a + 1] = bv.y;
      r1[t][4 * a + 2] = bv.z; r1[t][4 * a + 3] = bv.w;
    }
  {
    const f16_t* rw1 = ws + RW1F_OFF;
    #pragma unroll
    for (int t = 0; t < 2; ++t)
      #pragma unroll
      for (int ks = 0; ks < 8; ++ks) {
        f16x8 wf = *reinterpret_cast<const f16x8*>(rw1 + (t * 8 + ks) * 512 + lane16);
        r1[t] = __builtin_amdgcn_mfma_f32_32x32x16_f16(wf, poolf[ks], r1[t], 0, 0, 0);
      }
  }
  #pragma unroll
  for (int t = 0; t < 2; ++t)
    #pragma unroll
    for (int r = 0; r < 16; ++r) r1[t][r] = fmaxf(r1[t][r], 0.f);

  // ---- R2 (swapped): r2^T = rW2T x r1^T, K=64 ----
  f16x8 r1f[4];
  xpose2(r1[0], xrow0, lh, r1f[0], r1f[1]);
  xpose2(r1[1], xrow1, lh, r1f[2], r1f[3]);
  f32x16 r2[2];
  #pragma unroll
  for (int t = 0; t < 2; ++t)
    #pragma unroll
    for (int a = 0; a < 4; ++a) {
      float4 bv = *reinterpret_cast<const float4*>(&rb_lds[64 + t * 32 + a * 8 + lh * 4]);
      r2[t][4 * a + 0] = bv.x; r2[t][4 * a + 1] = bv.y;
      r2[t][4 * a + 2] = bv.z; r2[t][4 * a + 3] = bv.w;
    }
  {
    const f16_t* rw2 = ws + RW2F_OFF;
    #pragma unroll
    for (int t = 0; t < 2; ++t)
      #pragma unroll
      for (int ks = 0; ks < 4; ++ks) {
        f16x8 wf = *reinterpret_cast<const f16x8*>(rw2 + (t * 4 + ks) * 512 + lane16);
        r2[t] = __builtin_amdgcn_mfma_f32_32x32x16_f16(wf, r1f[ks], r2[t], 0, 0, 0);
      }
  }
  #pragma unroll
  for (int t = 0; t < 2; ++t)
    #pragma unroll
    for (int r = 0; r < 16; ++r) r2[t][r] = fmaxf(r2[t][r], 0.f);

  // ---- R3 (NON-swapped for coalesced stores): o = r2 @ rW3, N=128 ----
  f16x8 r2f[4];
  xpose2(r2[0], xrow0, lh, r2f[0], r2f[1]);
  xpose2(r2[1], xrow1, lh, r2f[2], r2f[3]);
  f32x16 oacc[4] = {};
  {
    const f16_t* rw3 = ws + RW3F_OFF;
    #pragma unroll
    for (int nt = 0; nt < 4; ++nt)
      #pragma unroll
      for (int ks = 0; ks < 4; ++ks) {
        f16x8 wf = *reinterpret_cast<const f16x8*>(rw3 + (nt * 4 + ks) * 512 + lane16);
        oacc[nt] = __builtin_amdgcn_mfma_f32_32x32x16_f16(r2f[ks], wf, oacc[nt], 0, 0, 0);
      }
  }
  const int rowb = row0 + wid * 32;
  #pragma unroll
  for (int nt = 0; nt < 4; ++nt) {
    float rbv = rb_lds[128 + nt * 32 + l31];
    #pragma unroll
    for (int r = 0; r < 16; ++r) {
      int rl = (r & 3) + 8 * (r >> 2) + 4 * lh;
      size_t grow = (size_t)(rowb + rl);
      float v = oacc[nt][r] + rbv;
      if (nt < 2) {
        out[grow * 64 + nt * 32 + l31] = v;
      } else {
        float sp = fmaxf(v, 0.f) + __logf(1.f + __expf(-fabsf(v)));
        out[(size_t)SIG_OFF + grow * 64 + (nt - 2) * 32 + l31] = sp;
      }
    }
  }
}

extern "C" void kernel_launch(void* const* d_in, const int* in_sizes, int n_in,
                              void* d_out, int out_size, void* d_ws, size_t ws_size,
                              hipStream_t stream) {
  const float* x    = (const float*)d_in[0];
  const int*   mask = (const int*)d_in[1];
  const float* W1   = (const float*)d_in[2];
  const float* b1   = (const float*)d_in[3];
  const float* W2   = (const float*)d_in[4];
  const float* b2   = (const float*)d_in[5];
  const float* W3   = (const float*)d_in[6];
  const float* b3   = (const float*)d_in[7];
  const float* rW1  = (const float*)d_in[8];
  const float* rb1  = (const float*)d_in[9];
  const float* rW2  = (const float*)d_in[10];
  const float* rb2  = (const float*)d_in[11];
  const float* rW3  = (const float*)d_in[12];
  const float* rb3  = (const float*)d_in[13];
  float* out = (float*)d_out;
  f16_t* ws = (f16_t*)d_ws;

  convert_weights<<<256, 256, 0, stream>>>(W1, b1, W2, W3, b3, rW1, rW2, rW3, ws);
  indexnet_main<<<NROWS / 128, 256, 0, stream>>>(
      x, mask, b2, rb1, rb2, rb3, ws, out);
}

// Round 9
// 57.134 us; speedup vs baseline: 1.4193x; 1.0892x over previous
//
#include <hip/hip_runtime.h>
#include <hip/hip_bf16.h>
#include <math.h>

typedef _Float16 f16_t;
typedef _Float16 f16x8 __attribute__((ext_vector_type(8)));
typedef float f32x16 __attribute__((ext_vector_type(16)));
typedef unsigned int uintx4 __attribute__((ext_vector_type(4)));
typedef unsigned int uintx2 __attribute__((ext_vector_type(2)));

#define NROWS 32768
#define DD 32
#define SIG_OFF (NROWS * 64)

// ---------------- ws layout (f16 elements) ----------------
// GEMM weights in PER-WAVE FRAGMENT-LOAD ORDER: [tile][ks][lane][j(0..7)],
// lane = l31 + 32*lh; n = tile*32 + l31; k = ks*16 + lh*8 + j.
// Per-d superblock: wf2(4096) | wf3(8192) = 12288 f16 = 24KB.
#define PERD_STRIDE 12288
#define W1B1F_OFF  393216          // [32 d][128] : w1[0..63] | b1[64..127]
#define RW1F_OFF   397312          // 2t x 8ks x 512 (rW1[k][n], k<128)
#define RW2F_OFF   405504          // 2t x 4ks x 512 (rW2[k][n], k<64)
#define RW3F_OFF   409600          // 4nt x 4ks x 512 (rW3[k][n], n<128)
#define B3F_OFF    417792          // 4t x 2ks x 512 (b3[d][n] as B-frag, "k"=d)
#define WS_ELEMS   421888

__global__ void convert_weights(const float* __restrict__ W1,
                                const float* __restrict__ b1,
                                const float* __restrict__ W2,
                                const float* __restrict__ W3,
                                const float* __restrict__ b3,
                                const float* __restrict__ rW1,
                                const float* __restrict__ rW2,
                                const float* __restrict__ rW3,
                                f16_t* __restrict__ ws) {
  for (int i = blockIdx.x * blockDim.x + threadIdx.x; i < WS_ELEMS;
       i += gridDim.x * blockDim.x) {
    float v;
    if (i < W1B1F_OFF) {
      int d = i / PERD_STRIDE;
      int r = i - d * PERD_STRIDE;
      if (r < 4096) {                 // wf2 fragments: W2[d][k][n], n<64
        int t = r >> 11, ks = (r >> 9) & 3, lane = (r >> 3) & 63, j = r & 7;
        int n = t * 32 + (lane & 31);
        int k = ks * 16 + (lane >> 5) * 8 + j;
        v = W2[(d * 64 + k) * 64 + n];
      } else {                        // wf3 fragments: W3[d][k][n], n<128
        int r2 = r - 4096;
        int t = r2 >> 11, ks = (r2 >> 9) & 3, lane = (r2 >> 3) & 63, j = r2 & 7;
        int n = t * 32 + (lane & 31);
        int k = ks * 16 + (lane >> 5) * 8 + j;
        v = W3[(d * 64 + k) * 128 + n];
      }
    } else if (i < RW1F_OFF) {        // w1 | b1, [d][128]
      int jj = i - W1B1F_OFF;
      int d = jj >> 7, c = jj & 127;
      v = (c < 64) ? W1[d * 64 + c] : b1[d * 64 + (c - 64)];
    } else if (i < RW2F_OFF) {        // rW1 fragments, k<128
      int i2 = i - RW1F_OFF;
      int t = i2 >> 12, ks = (i2 >> 9) & 7, lane = (i2 >> 3) & 63, j = i2 & 7;
      int n = t * 32 + (lane & 31);
      int k = ks * 16 + (lane >> 5) * 8 + j;
      v = rW1[k * 64 + n];
    } else if (i < RW3F_OFF) {        // rW2 fragments, k<64
      int i2 = i - RW2F_OFF;
      int t = i2 >> 11, ks = (i2 >> 9) & 3, lane = (i2 >> 3) & 63, j = i2 & 7;
      int n = t * 32 + (lane & 31);
      int k = ks * 16 + (lane >> 5) * 8 + j;
      v = rW2[k * 64 + n];
    } else if (i < B3F_OFF) {         // rW3 fragments, output col n<128, k<64
      int i2 = i - RW3F_OFF;
      int nt = i2 >> 11, ks = (i2 >> 9) & 3, lane = (i2 >> 3) & 63, j = i2 & 7;
      int n = nt * 32 + (lane & 31);
      int k = ks * 16 + (lane >> 5) * 8 + j;
      v = rW3[k * 128 + n];
    } else {                          // b3 as B-fragment: "k" axis = d (32)
      int i2 = i - B3F_OFF;
      int t = i2 >> 10, ks = (i2 >> 9) & 1, lane = (i2 >> 3) & 63, j = i2 & 7;
      int n = t * 32 + (lane & 31);
      int dsrc = ks * 16 + (lane >> 5) * 8 + j;
      v = b3[dsrc * 128 + n];
    }
    ws[i] = (f16_t)v;
  }
}

// Swapped-C tile (lane = data-row l31, regs: n=(reg&3)+8*(reg>>2)+4*lh) ->
// two B fragments via a PER-WAVE private LDS round-trip (no barrier; the
// within-wave ds_write->ds_read dependence is compiler-ordered).
__device__ __forceinline__ void xpose2(const f32x16& c, unsigned* row, int lh,
                                       f16x8& o0, f16x8& o1) {
  #pragma unroll
  for (int a = 0; a < 4; ++a) {
    uintx2 w;
    w.x = __builtin_bit_cast(unsigned, __builtin_amdgcn_cvt_pkrtz(c[4 * a + 0], c[4 * a + 1]));
    w.y = __builtin_bit_cast(unsigned, __builtin_amdgcn_cvt_pkrtz(c[4 * a + 2], c[4 * a + 3]));
    *reinterpret_cast<uintx2*>(row + 4 * a + 2 * lh) = w;
  }
  uintx2 ra = *reinterpret_cast<const uintx2*>(row + 4 * lh);
  uintx2 rb = *reinterpret_cast<const uintx2*>(row + 4 * lh + 2);
  uintx2 rc = *reinterpret_cast<const uintx2*>(row + 8 + 4 * lh);
  uintx2 rd = *reinterpret_cast<const uintx2*>(row + 8 + 4 * lh + 2);
  uintx4 w0 = {ra.x, ra.y, rb.x, rb.y};
  uintx4 w1 = {rc.x, rc.y, rd.x, rd.y};
  o0 = __builtin_bit_cast(f16x8, w0);
  o1 = __builtin_bit_cast(f16x8, w1);
}

// One d-iteration of Phase A: h1 -> GEMM1(swapped) -> relu/mask -> xpose ->
// GEMM2(swapped, accumulate into pooled acc). All straight-line; callers put
// two of these back-to-back so the scheduler interleaves the two chains.
__device__ __forceinline__ void compute_d(const f16_t* __restrict__ wb,
                                          const f16_t* __restrict__ w1b1row,
                                          const float* __restrict__ b2row,
                                          unsigned* xr0, unsigned* xr1,
                                          float xv, bool mb,
                                          int lane16, int lh, f32x16* acc) {
  f16x8 wf2[2][4], wf3[4][4];
  #pragma unroll
  for (int t = 0; t < 2; ++t)
    #pragma unroll
    for (int ks = 0; ks < 4; ++ks)
      wf2[t][ks] = *reinterpret_cast<const f16x8*>(wb + (t * 4 + ks) * 512 + lane16);
  #pragma unroll
  for (int t = 0; t < 4; ++t)
    #pragma unroll
    for (int ks = 0; ks < 4; ++ks)
      wf3[t][ks] = *reinterpret_cast<const f16x8*>(wb + 4096 + (t * 4 + ks) * 512 + lane16);

  f16_t xh = (f16_t)xv;
  f16x8 xv8 = {xh, xh, xh, xh, xh, xh, xh, xh};
  f16x8 h1f[4];
  #pragma unroll
  for (int ks = 0; ks < 4; ++ks) {
    f16x8 w1 = *reinterpret_cast<const f16x8*>(w1b1row + ks * 16 + lh * 8);
    f16x8 bb = *reinterpret_cast<const f16x8*>(w1b1row + 64 + ks * 16 + lh * 8);
    f16x8 h = xv8 * w1 + bb;
    h1f[ks] = __builtin_elementwise_max(h, (f16x8)(f16_t)0);
  }

  f32x16 hacc[2];
  #pragma unroll
  for (int t = 0; t < 2; ++t)
    #pragma unroll
    for (int a = 0; a < 4; ++a) {
      float4 bv = *reinterpret_cast<const float4*>(b2row + t * 32 + a * 8 + lh * 4);
      hacc[t][4 * a + 0] = bv.x; hacc[t][4 * a + 1] = bv.y;
      hacc[t][4 * a + 2] = bv.z; hacc[t][4 * a + 3] = bv.w;
    }
  #pragma unroll
  for (int ks = 0; ks < 4; ++ks) {
    hacc[0] = __builtin_amdgcn_mfma_f32_32x32x16_f16(wf2[0][ks], h1f[ks], hacc[0], 0, 0, 0);
    hacc[1] = __builtin_amdgcn_mfma_f32_32x32x16_f16(wf2[1][ks], h1f[ks], hacc[1], 0, 0, 0);
  }
  #pragma unroll
  for (int t = 0; t < 2; ++t)
    #pragma unroll
    for (int r = 0; r < 16; ++r) {
      float v = fmaxf(hacc[t][r], 0.f);
      hacc[t][r] = mb ? v : 0.f;
    }
  f16x8 pf[4];
  xpose2(hacc[0], xr0, lh, pf[0], pf[1]);
  xpose2(hacc[1], xr1, lh, pf[2], pf[3]);
  #pragma unroll
  for (int t = 0; t < 4; ++t)
    #pragma unroll
    for (int ks = 0; ks < 4; ++ks)
      acc[t] = __builtin_amdgcn_mfma_f32_32x32x16_f16(wf3[t][ks], pf[ks], acc[t], 0, 0, 0);
}

// Round 9 structure: block = 256 thr = 4 waves = 128 rows; all waves walk
// d=0..31 from LDS-staged weights. d-loop unrolled x2 with QUAD-buffered
// 24KB superblocks (compile-time buffer indices) and ONE barrier per 2 d's:
// per phase {issue 12 global prefetch loads; compute_d(d); compute_d(d+1);
// write-late staged regs; barrier}. The two compute_d chains are independent
// (separate LDS buffers + separate xpose scratch slots) -> the scheduler
// interleaves them, hiding ds_read/xpose/MFMA latency that 1 wave/SIMD
// cannot hide via TLP (r8 post-mortem: 4650 cyc/iter vs ~1100 issue).
__launch_bounds__(256, 1)
__global__ void indexnet_main(const float* __restrict__ x,
                              const int* __restrict__ mask,
                              const float* __restrict__ b2,
                              const float* __restrict__ rb1,
                              const float* __restrict__ rb2,
                              const float* __restrict__ rb3,
                              const f16_t* __restrict__ ws,
                              float* __restrict__ out) {
  __shared__ __align__(16) f16_t wbuf[4][12288];       // 96KB weight quad-buf
  __shared__ __align__(16) f16_t w1b1_lds[32][128];    // 8KB
  __shared__ float b2_lds[32][64];                     // 8KB
  __shared__ float rb_lds[256];                        // rb1 | rb2 | rb3
  __shared__ __align__(16) unsigned xp_lds[4][4][32][18];  // per-wave, 4 slots

  const int tid = threadIdx.x;
  const int lane = tid & 63;
  const int wid = tid >> 6;
  const int l31 = lane & 31;
  const int lh = lane >> 5;
  const int row0 = blockIdx.x * 128;
  const int lane16 = lane * 8;            // f16 offset of lane's 16B chunk
  const int schunk = wid * 512 + lane16;  // thread's slot within a 4KB round

  unsigned* xpA0 = &xp_lds[wid][0][l31][0];
  unsigned* xpA1 = &xp_lds[wid][1][l31][0];
  unsigned* xpB0 = &xp_lds[wid][2][l31][0];
  unsigned* xpB1 = &xp_lds[wid][3][l31][0];

  // ---- stage b2 [32][64] f32 ----
  {
    float4* dst = reinterpret_cast<float4*>(&b2_lds[0][0]);
    const float4* src = reinterpret_cast<const float4*>(b2);
    dst[tid * 2] = src[tid * 2];
    dst[tid * 2 + 1] = src[tid * 2 + 1];
  }
  // ---- stage readout biases ----
  if (tid < 64)       rb_lds[tid] = rb1[tid];
  else if (tid < 128) rb_lds[tid] = rb2[tid - 64];
  else                rb_lds[tid] = rb3[tid - 128];
  // ---- stage w1|b1 [32][128] f16 (8KB) ----
  {
    const uintx4* src = reinterpret_cast<const uintx4*>(ws + W1B1F_OFF);
    uintx4* dst = reinterpret_cast<uintx4*>(&w1b1_lds[0][0]);
    dst[tid * 2] = src[tid * 2];
    dst[tid * 2 + 1] = src[tid * 2 + 1];
  }
  // ---- per-lane mask word for own row ----
  unsigned mword = 0;
  {
    const int4* mrow = reinterpret_cast<const int4*>(mask + (size_t)(row0 + wid * 32 + l31) * DD);
    #pragma unroll
    for (int c4 = 0; c4 < 8; ++c4) {
      int4 m = mrow[c4];
      mword |= (m.x != 0 ? 1u : 0u) << (4 * c4);
      mword |= (m.y != 0 ? 1u : 0u) << (4 * c4 + 1);
      mword |= (m.z != 0 ? 1u : 0u) << (4 * c4 + 2);
      mword |= (m.w != 0 ? 1u : 0u) << (4 * c4 + 3);
    }
  }
  const float* xrow = x + (size_t)(row0 + wid * 32 + l31) * DD;

  // ---- prologue: stage d=0 -> buf0, d=1 -> buf1 ----
  #pragma unroll
  for (int r = 0; r < 6; ++r) {
    f16x8 v0 = *reinterpret_cast<const f16x8*>(ws + r * 2048 + schunk);
    f16x8 v1 = *reinterpret_cast<const f16x8*>(ws + PERD_STRIDE + r * 2048 + schunk);
    *reinterpret_cast<f16x8*>(&wbuf[0][r * 2048 + schunk]) = v0;
    *reinterpret_cast<f16x8*>(&wbuf[1][r * 2048 + schunk]) = v1;
  }
  __syncthreads();   // staging + b2/rb/w1b1 ready

  f32x16 acc[4] = {};   // pooled^T: tile t -> n = 32t + rl, lane = row

  for (int dd0 = 0; dd0 < 32; dd0 += 4) {
    float4 xv4 = *reinterpret_cast<const float4*>(xrow + dd0);

    // ===== phase 1: compute dd0(buf0), dd0+1(buf1); stage dd0+2->buf2, dd0+3->buf3
    {
      f16x8 sA[6], sB[6];
      const f16_t* srcA = ws + (size_t)(dd0 + 2) * PERD_STRIDE + schunk;
      const f16_t* srcB = ws + (size_t)(dd0 + 3) * PERD_STRIDE + schunk;
      #pragma unroll
      for (int r = 0; r < 6; ++r) {
        sA[r] = *reinterpret_cast<const f16x8*>(srcA + r * 2048);
        sB[r] = *reinterpret_cast<const f16x8*>(srcB + r * 2048);
      }
      compute_d(&wbuf[0][0], &w1b1_lds[dd0][0], &b2_lds[dd0][0],
                xpA0, xpA1, xv4.x, (mword >> dd0) & 1u, lane16, lh, acc);
      compute_d(&wbuf[1][0], &w1b1_lds[dd0 + 1][0], &b2_lds[dd0 + 1][0],
                xpB0, xpB1, xv4.y, (mword >> (dd0 + 1)) & 1u, lane16, lh, acc);
      #pragma unroll
      for (int r = 0; r < 6; ++r) {
        *reinterpret_cast<f16x8*>(&wbuf[2][r * 2048 + schunk]) = sA[r];
        *reinterpret_cast<f16x8*>(&wbuf[3][r * 2048 + schunk]) = sB[r];
      }
      __syncthreads();
    }

    // ===== phase 2: compute dd0+2(buf2), dd0+3(buf3); stage dd0+4->buf0, dd0+5->buf1
    {
      const bool pf = (dd0 < 28);
      f16x8 sA[6], sB[6];
      if (pf) {
        const f16_t* srcA = ws + (size_t)(dd0 + 4) * PERD_STRIDE + schunk;
        const f16_t* srcB = ws + (size_t)(dd0 + 5) * PERD_STRIDE + schunk;
        #pragma unroll
        for (int r = 0; r < 6; ++r) {
          sA[r] = *reinterpret_cast<const f16x8*>(srcA + r * 2048);
          sB[r] = *reinterpret_cast<const f16x8*>(srcB + r * 2048);
        }
      }
      compute_d(&wbuf[2][0], &w1b1_lds[dd0 + 2][0], &b2_lds[dd0 + 2][0],
                xpA0, xpA1, xv4.z, (mword >> (dd0 + 2)) & 1u, lane16, lh, acc);
      compute_d(&wbuf[3][0], &w1b1_lds[dd0 + 3][0], &b2_lds[dd0 + 3][0],
                xpB0, xpB1, xv4.w, (mword >> (dd0 + 3)) & 1u, lane16, lh, acc);
      if (pf) {
        #pragma unroll
        for (int r = 0; r < 6; ++r) {
          *reinterpret_cast<f16x8*>(&wbuf[0][r * 2048 + schunk]) = sA[r];
          *reinterpret_cast<f16x8*>(&wbuf[1][r * 2048 + schunk]) = sB[r];
        }
      }
      __syncthreads();
    }
  }

  // ---- pooled += maskT @ b3 (bias of masked sum), 8 MFMA ----
  {
    f16x8 mf[2];
    #pragma unroll
    for (int ks = 0; ks < 2; ++ks) {
      unsigned w[4];
      #pragma unroll
      for (int i = 0; i < 4; ++i) {
        int d0 = ks * 16 + lh * 8 + 2 * i;
        w[i] = (((mword >> d0) & 1u) ? 0x3C00u : 0u) |
               (((mword >> (d0 + 1)) & 1u) ? 0x3C000000u : 0u);
      }
      uintx4 ww = {w[0], w[1], w[2], w[3]};
      mf[ks] = __builtin_bit_cast(f16x8, ww);
    }
    const f16_t* b3f = ws + B3F_OFF;
    #pragma unroll
    for (int t = 0; t < 4; ++t)
      #pragma unroll
      for (int ks = 0; ks < 2; ++ks) {
        f16x8 bf = *reinterpret_cast<const f16x8*>(b3f + (t * 2 + ks) * 512 + lane16);
        acc[t] = __builtin_amdgcn_mfma_f32_32x32x16_f16(bf, mf[ks], acc[t], 0, 0, 0);
      }
  }

  // ---- R1 (swapped): r1^T = rW1T x pooled^T, K=128 ----
  f16x8 poolf[8];
  xpose2(acc[0], xpA0, lh, poolf[0], poolf[1]);
  xpose2(acc[1], xpA1, lh, poolf[2], poolf[3]);
  xpose2(acc[2], xpB0, lh, poolf[4], poolf[5]);
  xpose2(acc[3], xpB1, lh, poolf[6], poolf[7]);
  f32x16 r1[2];
  #pragma unroll
  for (int t = 0; t < 2; ++t)
    #pragma unroll
    for (int a = 0; a < 4; ++a) {
      float4 bv = *reinterpret_cast<const float4*>(&rb_lds[t * 32 + a * 8 + lh * 4]);
      r1[t][4 * a + 0] = bv.x; r1[t][4 * a + 1] = bv.y;
      r1[t][4 * a + 2] = bv.z; r1[t][4 * a + 3] = bv.w;
    }
  {
    const f16_t* rw1 = ws + RW1F_OFF;
    #pragma unroll
    for (int t = 0; t < 2; ++t)
      #pragma unroll
      for (int ks = 0; ks < 8; ++ks) {
        f16x8 wf = *reinterpret_cast<const f16x8*>(rw1 + (t * 8 + ks) * 512 + lane16);
        r1[t] = __builtin_amdgcn_mfma_f32_32x32x16_f16(wf, poolf[ks], r1[t], 0, 0, 0);
      }
  }
  #pragma unroll
  for (int t = 0; t < 2; ++t)
    #pragma unroll
    for (int r = 0; r < 16; ++r) r1[t][r] = fmaxf(r1[t][r], 0.f);

  // ---- R2 (swapped): r2^T = rW2T x r1^T, K=64 ----
  f16x8 r1f[4];
  xpose2(r1[0], xpA0, lh, r1f[0], r1f[1]);
  xpose2(r1[1], xpA1, lh, r1f[2], r1f[3]);
  f32x16 r2[2];
  #pragma unroll
  for (int t = 0; t < 2; ++t)
    #pragma unroll
    for (int a = 0; a < 4; ++a) {
      float4 bv = *reinterpret_cast<const float4*>(&rb_lds[64 + t * 32 + a * 8 + lh * 4]);
      r2[t][4 * a + 0] = bv.x; r2[t][4 * a + 1] = bv.y;
      r2[t][4 * a + 2] = bv.z; r2[t][4 * a + 3] = bv.w;
    }
  {
    const f16_t* rw2 = ws + RW2F_OFF;
    #pragma unroll
    for (int t = 0; t < 2; ++t)
      #pragma unroll
      for (int ks = 0; ks < 4; ++ks) {
        f16x8 wf = *reinterpret_cast<const f16x8*>(rw2 + (t * 4 + ks) * 512 + lane16);
        r2[t] = __builtin_amdgcn_mfma_f32_32x32x16_f16(wf, r1f[ks], r2[t], 0, 0, 0);
      }
  }
  #pragma unroll
  for (int t = 0; t < 2; ++t)
    #pragma unroll
    for (int r = 0; r < 16; ++r) r2[t][r] = fmaxf(r2[t][r], 0.f);

  // ---- R3 (NON-swapped for coalesced stores): o = r2 @ rW3, N=128 ----
  f16x8 r2f[4];
  xpose2(r2[0], xpA0, lh, r2f[0], r2f[1]);
  xpose2(r2[1], xpA1, lh, r2f[2], r2f[3]);
  f32x16 oacc[4] = {};
  {
    const f16_t* rw3 = ws + RW3F_OFF;
    #pragma unroll
    for (int nt = 0; nt < 4; ++nt)
      #pragma unroll
      for (int ks = 0; ks < 4; ++ks) {
        f16x8 wf = *reinterpret_cast<const f16x8*>(rw3 + (nt * 4 + ks) * 512 + lane16);
        oacc[nt] = __builtin_amdgcn_mfma_f32_32x32x16_f16(r2f[ks], wf, oacc[nt], 0, 0, 0);
      }
  }
  const int rowb = row0 + wid * 32;
  #pragma unroll
  for (int nt = 0; nt < 4; ++nt) {
    float rbv = rb_lds[128 + nt * 32 + l31];
    #pragma unroll
    for (int r = 0; r < 16; ++r) {
      int rl = (r & 3) + 8 * (r >> 2) + 4 * lh;
      size_t grow = (size_t)(rowb + rl);
      float v = oacc[nt][r] + rbv;
      if (nt < 2) {
        out[grow * 64 + nt * 32 + l31] = v;
      } else {
        float sp = fmaxf(v, 0.f) + __logf(1.f + __expf(-fabsf(v)));
        out[(size_t)SIG_OFF + grow * 64 + (nt - 2) * 32 + l31] = sp;
      }
    }
  }
}

extern "C" void kernel_launch(void* const* d_in, const int* in_sizes, int n_in,
                              void* d_out, int out_size, void* d_ws, size_t ws_size,
                              hipStream_t stream) {
  const float* x    = (const float*)d_in[0];
  const int*   mask = (const int*)d_in[1];
  const float* W1   = (const float*)d_in[2];
  const float* b1   = (const float*)d_in[3];
  const float* W2   = (const float*)d_in[4];
  const float* b2   = (const float*)d_in[5];
  const float* W3   = (const float*)d_in[6];
  const float* b3   = (const float*)d_in[7];
  const float* rW1  = (const float*)d_in[8];
  const float* rb1  = (const float*)d_in[9];
  const float* rW2  = (const float*)d_in[10];
  const float* rb2  = (const float*)d_in[11];
  const float* rW3  = (const float*)d_in[12];
  const float* rb3  = (const float*)d_in[13];
  float* out = (float*)d_out;
  f16_t* ws = (f16_t*)d_ws;

  convert_weights<<<256, 256, 0, stream>>>(W1, b1, W2, W3, b3, rW1, rW2, rW3, ws);
  indexnet_main<<<NROWS / 128, 256, 0, stream>>>(
      x, mask, b2, rb1, rb2, rb3, ws, out);
}

// Round 10
// 52.904 us; speedup vs baseline: 1.5328x; 1.0800x over previous
//
#include <hip/hip_runtime.h>
#include <hip/hip_bf16.h>
#include <math.h>

typedef _Float16 f16_t;
typedef _Float16 f16x8 __attribute__((ext_vector_type(8)));
typedef float f32x16 __attribute__((ext_vector_type(16)));
typedef unsigned int uintx4 __attribute__((ext_vector_type(4)));
typedef unsigned int uintx2 __attribute__((ext_vector_type(2)));

#define NROWS 32768
#define DD 32
#define SIG_OFF (NROWS * 64)

// ---------------- ws layout (f16 elements) ----------------
// GEMM weights in PER-WAVE FRAGMENT-LOAD ORDER: [tile][ks][lane][j(0..7)],
// lane = l31 + 32*lh; n = tile*32 + l31; k = ks*16 + lh*8 + j.
// Per-d superblock: wf2(4096) | wf3(8192) = 12288 f16 = 24KB.
#define PERD_STRIDE 12288
#define W1B1F_OFF  393216          // [32 d][128] : w1[0..63] | b1[64..127]
#define RW1F_OFF   397312          // 2t x 8ks x 512 (rW1[k][n], k<128)
#define RW2F_OFF   405504          // 2t x 4ks x 512 (rW2[k][n], k<64)
#define RW3F_OFF   409600          // 4nt x 4ks x 512 (rW3[k][n], n<128)
#define B3F_OFF    417792          // 4t x 2ks x 512 (b3[d][n] as B-frag, "k"=d)
#define WS_ELEMS   421888

__global__ void convert_weights(const float* __restrict__ W1,
                                const float* __restrict__ b1,
                                const float* __restrict__ W2,
                                const float* __restrict__ W3,
                                const float* __restrict__ b3,
                                const float* __restrict__ rW1,
                                const float* __restrict__ rW2,
                                const float* __restrict__ rW3,
                                f16_t* __restrict__ ws) {
  for (int i = blockIdx.x * blockDim.x + threadIdx.x; i < WS_ELEMS;
       i += gridDim.x * blockDim.x) {
    float v;
    if (i < W1B1F_OFF) {
      int d = i / PERD_STRIDE;
      int r = i - d * PERD_STRIDE;
      if (r < 4096) {                 // wf2 fragments: W2[d][k][n], n<64
        int t = r >> 11, ks = (r >> 9) & 3, lane = (r >> 3) & 63, j = r & 7;
        int n = t * 32 + (lane & 31);
        int k = ks * 16 + (lane >> 5) * 8 + j;
        v = W2[(d * 64 + k) * 64 + n];
      } else {                        // wf3 fragments: W3[d][k][n], n<128
        int r2 = r - 4096;
        int t = r2 >> 11, ks = (r2 >> 9) & 3, lane = (r2 >> 3) & 63, j = r2 & 7;
        int n = t * 32 + (lane & 31);
        int k = ks * 16 + (lane >> 5) * 8 + j;
        v = W3[(d * 64 + k) * 128 + n];
      }
    } else if (i < RW1F_OFF) {        // w1 | b1, [d][128]
      int jj = i - W1B1F_OFF;
      int d = jj >> 7, c = jj & 127;
      v = (c < 64) ? W1[d * 64 + c] : b1[d * 64 + (c - 64)];
    } else if (i < RW2F_OFF) {        // rW1 fragments, k<128
      int i2 = i - RW1F_OFF;
      int t = i2 >> 12, ks = (i2 >> 9) & 7, lane = (i2 >> 3) & 63, j = i2 & 7;
      int n = t * 32 + (lane & 31);
      int k = ks * 16 + (lane >> 5) * 8 + j;
      v = rW1[k * 64 + n];
    } else if (i < RW3F_OFF) {        // rW2 fragments, k<64
      int i2 = i - RW2F_OFF;
      int t = i2 >> 11, ks = (i2 >> 9) & 3, lane = (i2 >> 3) & 63, j = i2 & 7;
      int n = t * 32 + (lane & 31);
      int k = ks * 16 + (lane >> 5) * 8 + j;
      v = rW2[k * 64 + n];
    } else if (i < B3F_OFF) {         // rW3 fragments, output col n<128, k<64
      int i2 = i - RW3F_OFF;
      int nt = i2 >> 11, ks = (i2 >> 9) & 3, lane = (i2 >> 3) & 63, j = i2 & 7;
      int n = nt * 32 + (lane & 31);
      int k = ks * 16 + (lane >> 5) * 8 + j;
      v = rW3[k * 128 + n];
    } else {                          // b3 as B-fragment: "k" axis = d (32)
      int i2 = i - B3F_OFF;
      int t = i2 >> 10, ks = (i2 >> 9) & 1, lane = (i2 >> 3) & 63, j = i2 & 7;
      int n = t * 32 + (lane & 31);
      int dsrc = ks * 16 + (lane >> 5) * 8 + j;
      v = b3[dsrc * 128 + n];
    }
    ws[i] = (f16_t)v;
  }
}

// Swapped-C tile (lane = data-row l31, regs: n=(reg&3)+8*(reg>>2)+4*lh) ->
// two B fragments via a PER-WAVE private LDS round-trip (no barrier; the
// within-wave ds_write->ds_read dependence is compiler-ordered).
__device__ __forceinline__ void xpose2(const f32x16& c, unsigned* row, int lh,
                                       f16x8& o0, f16x8& o1) {
  #pragma unroll
  for (int a = 0; a < 4; ++a) {
    uintx2 w;
    w.x = __builtin_bit_cast(unsigned, __builtin_amdgcn_cvt_pkrtz(c[4 * a + 0], c[4 * a + 1]));
    w.y = __builtin_bit_cast(unsigned, __builtin_amdgcn_cvt_pkrtz(c[4 * a + 2], c[4 * a + 3]));
    *reinterpret_cast<uintx2*>(row + 4 * a + 2 * lh) = w;
  }
  uintx2 ra = *reinterpret_cast<const uintx2*>(row + 4 * lh);
  uintx2 rb = *reinterpret_cast<const uintx2*>(row + 4 * lh + 2);
  uintx2 rc = *reinterpret_cast<const uintx2*>(row + 8 + 4 * lh);
  uintx2 rd = *reinterpret_cast<const uintx2*>(row + 8 + 4 * lh + 2);
  uintx4 w0 = {ra.x, ra.y, rb.x, rb.y};
  uintx4 w1 = {rc.x, rc.y, rd.x, rd.y};
  o0 = __builtin_bit_cast(f16x8, w0);
  o1 = __builtin_bit_cast(f16x8, w1);
}

// One d-iteration of Phase A: h1 -> GEMM1(swapped) -> relu/mask -> xpose ->
// GEMM2(swapped, accumulate into pooled acc).
__device__ __forceinline__ void compute_d(const f16_t* __restrict__ wb,
                                          const f16_t* __restrict__ w1b1row,
                                          const float* __restrict__ b2row,
                                          unsigned* xr0, unsigned* xr1,
                                          float xv, bool mb,
                                          int lane16, int lh, f32x16* acc) {
  f16x8 wf2[2][4], wf3[4][4];
  #pragma unroll
  for (int t = 0; t < 2; ++t)
    #pragma unroll
    for (int ks = 0; ks < 4; ++ks)
      wf2[t][ks] = *reinterpret_cast<const f16x8*>(wb + (t * 4 + ks) * 512 + lane16);
  #pragma unroll
  for (int t = 0; t < 4; ++t)
    #pragma unroll
    for (int ks = 0; ks < 4; ++ks)
      wf3[t][ks] = *reinterpret_cast<const f16x8*>(wb + 4096 + (t * 4 + ks) * 512 + lane16);

  f16_t xh = (f16_t)xv;
  f16x8 xv8 = {xh, xh, xh, xh, xh, xh, xh, xh};
  f16x8 h1f[4];
  #pragma unroll
  for (int ks = 0; ks < 4; ++ks) {
    f16x8 w1 = *reinterpret_cast<const f16x8*>(w1b1row + ks * 16 + lh * 8);
    f16x8 bb = *reinterpret_cast<const f16x8*>(w1b1row + 64 + ks * 16 + lh * 8);
    f16x8 h = xv8 * w1 + bb;
    h1f[ks] = __builtin_elementwise_max(h, (f16x8)(f16_t)0);
  }

  f32x16 hacc[2];
  #pragma unroll
  for (int t = 0; t < 2; ++t)
    #pragma unroll
    for (int a = 0; a < 4; ++a) {
      float4 bv = *reinterpret_cast<const float4*>(b2row + t * 32 + a * 8 + lh * 4);
      hacc[t][4 * a + 0] = bv.x; hacc[t][4 * a + 1] = bv.y;
      hacc[t][4 * a + 2] = bv.z; hacc[t][4 * a + 3] = bv.w;
    }
  #pragma unroll
  for (int ks = 0; ks < 4; ++ks) {
    hacc[0] = __builtin_amdgcn_mfma_f32_32x32x16_f16(wf2[0][ks], h1f[ks], hacc[0], 0, 0, 0);
    hacc[1] = __builtin_amdgcn_mfma_f32_32x32x16_f16(wf2[1][ks], h1f[ks], hacc[1], 0, 0, 0);
  }
  #pragma unroll
  for (int t = 0; t < 2; ++t)
    #pragma unroll
    for (int r = 0; r < 16; ++r) {
      float v = fmaxf(hacc[t][r], 0.f);
      hacc[t][r] = mb ? v : 0.f;
    }
  f16x8 pf[4];
  xpose2(hacc[0], xr0, lh, pf[0], pf[1]);
  xpose2(hacc[1], xr1, lh, pf[2], pf[3]);
  #pragma unroll
  for (int t = 0; t < 4; ++t)
    #pragma unroll
    for (int ks = 0; ks < 4; ++ks)
      acc[t] = __builtin_amdgcn_mfma_f32_32x32x16_f16(wf3[t][ks], pf[ks], acc[t], 0, 0, 0);
}

// Round 10 structure: block = 512 thr = 8 waves. Wave (pr = wid>>1, q = wid&1):
// pr owns rows blk*128 + pr*32 + l31; q owns d-half [16q, 16q+16).
// TWO LDS weight streams (one per d-half), each double-buffered: 96KB.
// All 512 threads cooperatively stage both next superblocks (issue-early /
// write-late, 1 barrier per iteration, 16 iterations). This combines r8's
// LDS-staged weights (ds_read ~120cyc instead of L2 ~400cyc) with r4-7's
// q-split (2048 waves = 2 waves/SIMD) -- the first structure with BOTH cheap
// weight access AND a second wave per SIMD to hide the remaining latency
// (r8/r9 post-mortems: 1 wave/SIMD left ~70% of cycles as exposed stalls).
// Pool halves combine through a pool area aliased onto the dead wbuf.
__launch_bounds__(512, 2)
__global__ void indexnet_main(const float* __restrict__ x,
                              const int* __restrict__ mask,
                              const float* __restrict__ b2,
                              const float* __restrict__ rb1,
                              const float* __restrict__ rb2,
                              const float* __restrict__ rb3,
                              const f16_t* __restrict__ ws,
                              float* __restrict__ out) {
  __shared__ __align__(16) f16_t wbuf[2][2][12288];    // [q-stream][dbuf] 96KB
  __shared__ __align__(16) f16_t w1b1_lds[32][128];    // 8KB
  __shared__ float b2_lds[32][64];                     // 8KB
  __shared__ float rb_lds[256];                        // 1KB: rb1 | rb2 | rb3
  __shared__ __align__(16) unsigned xp_lds[8][2][32][18];  // 36.9KB xpose scratch
  // total ~152.6KB -> 1 block/CU, 8 waves/CU = 2 waves/SIMD

  const int tid = threadIdx.x;
  const int lane = tid & 63;
  const int wid = tid >> 6;
  const int pr = wid >> 1;         // row group (0..3)
  const int q = wid & 1;           // d-half
  const int l31 = lane & 31;
  const int lh = lane >> 5;
  const int row0 = blockIdx.x * 128;
  const int lane16 = lane * 8;     // f16 offset of lane's 16B fragment chunk

  unsigned* xr0 = &xp_lds[wid][0][l31][0];
  unsigned* xr1 = &xp_lds[wid][1][l31][0];

  // ---- stage b2 [32][64] f32 (512 x float4) ----
  {
    float4* dst = reinterpret_cast<float4*>(&b2_lds[0][0]);
    const float4* src = reinterpret_cast<const float4*>(b2);
    dst[tid] = src[tid];
  }
  // ---- stage readout biases ----
  if (tid < 64)        rb_lds[tid] = rb1[tid];
  else if (tid < 128)  rb_lds[tid] = rb2[tid - 64];
  else if (tid < 256)  rb_lds[tid] = rb3[tid - 128];
  // ---- stage w1|b1 [32][128] f16 (512 x 16B) ----
  {
    const uintx4* src = reinterpret_cast<const uintx4*>(ws + W1B1F_OFF);
    uintx4* dst = reinterpret_cast<uintx4*>(&w1b1_lds[0][0]);
    dst[tid] = src[tid];
  }
  // ---- per-lane mask word for own row ----
  unsigned mword = 0;
  {
    const int4* mrow = reinterpret_cast<const int4*>(mask + (size_t)(row0 + pr * 32 + l31) * DD);
    #pragma unroll
    for (int c4 = 0; c4 < 8; ++c4) {
      int4 m = mrow[c4];
      mword |= (m.x != 0 ? 1u : 0u) << (4 * c4);
      mword |= (m.y != 0 ? 1u : 0u) << (4 * c4 + 1);
      mword |= (m.z != 0 ? 1u : 0u) << (4 * c4 + 2);
      mword |= (m.w != 0 ? 1u : 0u) << (4 * c4 + 3);
    }
  }
  const float* xrow = x + (size_t)(row0 + pr * 32 + l31) * DD + q * 16;
  const int dbase = q * 16;

  // ---- prologue: stage d=0 -> wbuf[0][0], d=16 -> wbuf[1][0] ----
  {
    const f16_t* s0 = ws + tid * 8;                            // d = 0
    const f16_t* s1 = ws + (size_t)16 * PERD_STRIDE + tid * 8; // d = 16
    #pragma unroll
    for (int c = 0; c < 3; ++c) {
      f16x8 v0 = *reinterpret_cast<const f16x8*>(s0 + c * 4096);
      f16x8 v1 = *reinterpret_cast<const f16x8*>(s1 + c * 4096);
      *reinterpret_cast<f16x8*>(&wbuf[0][0][c * 4096 + tid * 8]) = v0;
      *reinterpret_cast<f16x8*>(&wbuf[1][0][c * 4096 + tid * 8]) = v1;
    }
  }
  __syncthreads();   // staging + b2/rb/w1b1 ready

  f32x16 acc[4] = {};   // pooled^T: tile t -> n = 32t + rl, lane = row
  float4 xv4;

  for (int i = 0; i < 16; ++i) {
    if ((i & 3) == 0) xv4 = *reinterpret_cast<const float4*>(xrow + i);
    const int cur = i & 1;
    const bool pf_on = (i < 15);

    // ---- issue next-superblock global loads for BOTH streams (issue-early)
    f16x8 s0a, s0b, s0c, s1a, s1b, s1c;
    if (pf_on) {
      const f16_t* s0 = ws + (size_t)(i + 1) * PERD_STRIDE + tid * 8;
      const f16_t* s1 = ws + (size_t)(i + 17) * PERD_STRIDE + tid * 8;
      s0a = *reinterpret_cast<const f16x8*>(s0);
      s0b = *reinterpret_cast<const f16x8*>(s0 + 4096);
      s0c = *reinterpret_cast<const f16x8*>(s0 + 8192);
      s1a = *reinterpret_cast<const f16x8*>(s1);
      s1b = *reinterpret_cast<const f16x8*>(s1 + 4096);
      s1c = *reinterpret_cast<const f16x8*>(s1 + 8192);
    }

    // ---- compute this wave's d from its stream's current buffer ----
    const int d = dbase + i;
    float xv = ((i & 3) == 0) ? xv4.x : ((i & 3) == 1) ? xv4.y
             : ((i & 3) == 2) ? xv4.z : xv4.w;
    compute_d(&wbuf[q][cur][0], &w1b1_lds[d][0], &b2_lds[d][0],
              xr0, xr1, xv, (mword >> d) & 1u, lane16, lh, acc);

    // ---- write staged superblocks to the other buffers (write-late) ----
    if (pf_on) {
      f16_t* w0 = &wbuf[0][cur ^ 1][tid * 8];
      f16_t* w1 = &wbuf[1][cur ^ 1][tid * 8];
      *reinterpret_cast<f16x8*>(w0)        = s0a;
      *reinterpret_cast<f16x8*>(w0 + 4096) = s0b;
      *reinterpret_cast<f16x8*>(w0 + 8192) = s0c;
      *reinterpret_cast<f16x8*>(w1)        = s1a;
      *reinterpret_cast<f16x8*>(w1 + 4096) = s1b;
      *reinterpret_cast<f16x8*>(w1 + 8192) = s1c;
    }
    __syncthreads();
  }

  // ---- pool combine across q-halves (pool area aliases dead wbuf) ----
  // layout: [pr][lh][row l31][68]
  float* pool_ex = reinterpret_cast<float*>(&wbuf[0][0][0]);
  float* prow = pool_ex + (((size_t)pr * 2 + lh) * 32 + l31) * 68;
  if (q == 1) {
    #pragma unroll
    for (int t = 0; t < 4; ++t)
      #pragma unroll
      for (int a = 0; a < 4; ++a) {
        float4 f = {acc[t][4 * a], acc[t][4 * a + 1], acc[t][4 * a + 2], acc[t][4 * a + 3]};
        *reinterpret_cast<float4*>(prow + (t * 4 + a) * 4) = f;
      }
  }
  __syncthreads();
  if (q == 1) return;

  #pragma unroll
  for (int t = 0; t < 4; ++t)
    #pragma unroll
    for (int a = 0; a < 4; ++a) {
      float4 f = *reinterpret_cast<const float4*>(prow + (t * 4 + a) * 4);
      acc[t][4 * a + 0] += f.x; acc[t][4 * a + 1] += f.y;
      acc[t][4 * a + 2] += f.z; acc[t][4 * a + 3] += f.w;
    }

  // ---- pooled += maskT @ b3 (bias of masked sum), 8 MFMA ----
  {
    f16x8 mf[2];
    #pragma unroll
    for (int ks = 0; ks < 2; ++ks) {
      unsigned w[4];
      #pragma unroll
      for (int ii = 0; ii < 4; ++ii) {
        int d0 = ks * 16 + lh * 8 + 2 * ii;
        w[ii] = (((mword >> d0) & 1u) ? 0x3C00u : 0u) |
                (((mword >> (d0 + 1)) & 1u) ? 0x3C000000u : 0u);
      }
      uintx4 ww = {w[0], w[1], w[2], w[3]};
      mf[ks] = __builtin_bit_cast(f16x8, ww);
    }
    const f16_t* b3f = ws + B3F_OFF;
    #pragma unroll
    for (int t = 0; t < 4; ++t)
      #pragma unroll
      for (int ks = 0; ks < 2; ++ks) {
        f16x8 bf = *reinterpret_cast<const f16x8*>(b3f + (t * 2 + ks) * 512 + lane16);
        acc[t] = __builtin_amdgcn_mfma_f32_32x32x16_f16(bf, mf[ks], acc[t], 0, 0, 0);
      }
  }

  // ---- R1 (swapped): r1^T = rW1T x pooled^T, K=128 ----
  f16x8 poolf[8];
  xpose2(acc[0], xr0, lh, poolf[0], poolf[1]);
  xpose2(acc[1], xr1, lh, poolf[2], poolf[3]);
  xpose2(acc[2], xr0, lh, poolf[4], poolf[5]);
  xpose2(acc[3], xr1, lh, poolf[6], poolf[7]);
  f32x16 r1[2];
  #pragma unroll
  for (int t = 0; t < 2; ++t)
    #pragma unroll
    for (int a = 0; a < 4; ++a) {
      float4 bv = *reinterpret_cast<const float4*>(&rb_lds[t * 32 + a * 8 + lh * 4]);
      r1[t][4 * a + 0] = bv.x; r1[t][4 * a + 1] = bv.y;
      r1[t][4 * a + 2] = bv.z; r1[t][4 * a + 3] = bv.w;
    }
  {
    const f16_t* rw1 = ws + RW1F_OFF;
    #pragma unroll
    for (int t = 0; t < 2; ++t)
      #pragma unroll
      for (int ks = 0; ks < 8; ++ks) {
        f16x8 wf = *reinterpret_cast<const f16x8*>(rw1 + (t * 8 + ks) * 512 + lane16);
        r1[t] = __builtin_amdgcn_mfma_f32_32x32x16_f16(wf, poolf[ks], r1[t], 0, 0, 0);
      }
  }
  #pragma unroll
  for (int t = 0; t < 2; ++t)
    #pragma unroll
    for (int r = 0; r < 16; ++r) r1[t][r] = fmaxf(r1[t][r], 0.f);

  // ---- R2 (swapped): r2^T = rW2T x r1^T, K=64 ----
  f16x8 r1f[4];
  xpose2(r1[0], xr0, lh, r1f[0], r1f[1]);
  xpose2(r1[1], xr1, lh, r1f[2], r1f[3]);
  f32x16 r2[2];
  #pragma unroll
  for (int t = 0; t < 2; ++t)
    #pragma unroll
    for (int a = 0; a < 4; ++a) {
      float4 bv = *reinterpret_cast<const float4*>(&rb_lds[64 + t * 32 + a * 8 + lh * 4]);
      r2[t][4 * a + 0] = bv.x; r2[t][4 * a + 1] = bv.y;
      r2[t][4 * a + 2] = bv.z; r2[t][4 * a + 3] = bv.w;
    }
  {
    const f16_t* rw2 = ws + RW2F_OFF;
    #pragma unroll
    for (int t = 0; t < 2; ++t)
      #pragma unroll
      for (int ks = 0; ks < 4; ++ks) {
        f16x8 wf = *reinterpret_cast<const f16x8*>(rw2 + (t * 4 + ks) * 512 + lane16);
        r2[t] = __builtin_amdgcn_mfma_f32_32x32x16_f16(wf, r1f[ks], r2[t], 0, 0, 0);
      }
  }
  #pragma unroll
  for (int t = 0; t < 2; ++t)
    #pragma unroll
    for (int r = 0; r < 16; ++r) r2[t][r] = fmaxf(r2[t][r], 0.f);

  // ---- R3 (NON-swapped for coalesced stores): o = r2 @ rW3, N=128 ----
  f16x8 r2f[4];
  xpose2(r2[0], xr0, lh, r2f[0], r2f[1]);
  xpose2(r2[1], xr1, lh, r2f[2], r2f[3]);
  f32x16 oacc[4] = {};
  {
    const f16_t* rw3 = ws + RW3F_OFF;
    #pragma unroll
    for (int nt = 0; nt < 4; ++nt)
      #pragma unroll
      for (int ks = 0; ks < 4; ++ks) {
        f16x8 wf = *reinterpret_cast<const f16x8*>(rw3 + (nt * 4 + ks) * 512 + lane16);
        oacc[nt] = __builtin_amdgcn_mfma_f32_32x32x16_f16(r2f[ks], wf, oacc[nt], 0, 0, 0);
      }
  }
  const int rowb = row0 + pr * 32;
  #pragma unroll
  for (int nt = 0; nt < 4; ++nt) {
    float rbv = rb_lds[128 + nt * 32 + l31];
    #pragma unroll
    for (int r = 0; r < 16; ++r) {
      int rl = (r & 3) + 8 * (r >> 2) + 4 * lh;
      size_t grow = (size_t)(rowb + rl);
      float v = oacc[nt][r] + rbv;
      if (nt < 2) {
        out[grow * 64 + nt * 32 + l31] = v;
      } else {
        float sp = fmaxf(v, 0.f) + __logf(1.f + __expf(-fabsf(v)));
        out[(size_t)SIG_OFF + grow * 64 + (nt - 2) * 32 + l31] = sp;
      }
    }
  }
}

extern "C" void kernel_launch(void* const* d_in, const int* in_sizes, int n_in,
                              void* d_out, int out_size, void* d_ws, size_t ws_size,
                              hipStream_t stream) {
  const float* x    = (const float*)d_in[0];
  const int*   mask = (const int*)d_in[1];
  const float* W1   = (const float*)d_in[2];
  const float* b1   = (const float*)d_in[3];
  const float* W2   = (const float*)d_in[4];
  const float* b2   = (const float*)d_in[5];
  const float* W3   = (const float*)d_in[6];
  const float* b3   = (const float*)d_in[7];
  const float* rW1  = (const float*)d_in[8];
  const float* rb1  = (const float*)d_in[9];
  const float* rW2  = (const float*)d_in[10];
  const float* rb2  = (const float*)d_in[11];
  const float* rW3  = (const float*)d_in[12];
  const float* rb3  = (const float*)d_in[13];
  float* out = (float*)d_out;
  f16_t* ws = (f16_t*)d_ws;

  convert_weights<<<256, 256, 0, stream>>>(W1, b1, W2, W3, b3, rW1, rW2, rW3, ws);
  indexnet_main<<<NROWS / 128, 512, 0, stream>>>(
      x, mask, b2, rb1, rb2, rb3, ws, out);
}